// Round 1
// 478.581 us; speedup vs baseline: 1.1610x; 1.1610x over previous
//
#include <hip/hip_runtime.h>
#include <stdint.h>
#include <stddef.h>

// BinaryLinearLayer: out[8192,4096] = x[8192,4096] @ sign(W[4096,4096])^T + sign(bias)[4096]
// Path A: cvt x -> bf16, sign(W) -> bf16, then 256x256-tile 8-phase bf16 MFMA GEMM
// (T1 XCD swizzle + T2 LDS XOR swizzle + T3/T4 counted-vmcnt phases + T5 setprio).
// Fallback (ws too small): fused 128^2 kernel converting during LDS staging.

#define MDIM 8192
#define NDIM 4096
#define KDIM 4096
#define NT   (KDIM / 64)   // 64 K-tiles of BK=64

typedef __attribute__((ext_vector_type(8))) short bf16x8;
typedef __attribute__((ext_vector_type(4))) float f32x4;

__device__ __forceinline__ short f2bf(float f) {
  union { float f; unsigned u; } a; a.f = f;
  unsigned r = a.u + 0x7FFFu + ((a.u >> 16) & 1u);
  return (short)(r >> 16);
}

__device__ __forceinline__ float fsign(float x) {
  return (x > 0.f) ? 1.f : ((x < 0.f) ? -1.f : 0.f);
}

// sign(x) directly as bf16 bits: +1 -> 0x3F80, -1 -> 0xBF80, 0 -> 0
__device__ __forceinline__ short signbf(float x) {
  return (x > 0.f) ? (short)0x3F80 : ((x < 0.f) ? (short)0xBF80 : (short)0);
}

__device__ __forceinline__ void gl_lds16(const void* g, void* l) {
  __builtin_amdgcn_global_load_lds(
      (const __attribute__((address_space(1))) unsigned*)g,
      (__attribute__((address_space(3))) unsigned*)l,
      16, 0, 0);
}

// ---------------- conversion kernels (path A) ----------------

__global__ void cvt_x_kernel(const float* __restrict__ x, short* __restrict__ o) {
  int i = blockIdx.x * blockDim.x + threadIdx.x;          // one float4 per thread
  float4 v = ((const float4*)x)[i];
  short4 s;
  s.x = f2bf(v.x); s.y = f2bf(v.y); s.z = f2bf(v.z); s.w = f2bf(v.w);
  ((short4*)o)[i] = s;
}

__global__ void cvt_w_kernel(const float* __restrict__ w, short* __restrict__ o) {
  int i = blockIdx.x * blockDim.x + threadIdx.x;
  float4 v = ((const float4*)w)[i];
  short4 s;
  s.x = signbf(v.x); s.y = signbf(v.y); s.z = signbf(v.z); s.w = signbf(v.w);
  ((short4*)o)[i] = s;
}

// ---------------- main GEMM: 256^2 tile, 8-phase schedule ----------------
// C[m,n] = sum_k A[m,k]*B[n,k] + sign(bias[n]);  A,B row-major K-contiguous bf16.
//
// LDS map (131072 B, double buffered):
//   buf b at b*65536:  A-tile [256 rows][64 bf16] at 0      (halves: rows 0-127, 128-255)
//                      B-tile [256 rows][64 bf16] at 32768
//   logical addr of (row r, col-byte cb): r*128 + cb; stored XOR-swizzled:
//   phys = r*128 + (cb ^ ((r&7)<<4))   -- 16B-granular involution, both sides.
//
// Staging: half-tile = 128 rows x 64 bf16 = 16 KB; 512 thr x 2 x 16B loads.
//   thread t, load q: LDS linear offset o = q*8192 + t*16 -> row q*64 + (t>>3),
//   source column pre-swizzled: chunk = (t&7) ^ ((t>>3)&7).

#define STAGE(BUF, HH, KTS) do {                                               \
    const short* _s = ((HH) < 2 ? aA + (size_t)((HH) * 128) * KDIM             \
                                : aB + (size_t)(((HH) - 2) * 128) * KDIM)      \
                      + (size_t)(KTS) * 64;                                    \
    char* _d = ldst + (BUF) * 65536 + (HH) * 16384;                            \
    gl_lds16(_s, _d);                                                          \
    gl_lds16(_s + (size_t)64 * KDIM, _d + 8192);                               \
  } while (0)

#define READ_A(QOFF) do {                                                      \
    _Pragma("unroll") for (int i = 0; i < 4; ++i) {                            \
      const int ro = so + arow + (QOFF) + i * 2048;                            \
      a[i][0] = *(const bf16x8*)(sm + ro + colp0);                             \
      a[i][1] = *(const bf16x8*)(sm + ro + colp1);                             \
    } } while (0)

#define READ_B(DST, QOFF) do {                                                 \
    _Pragma("unroll") for (int j = 0; j < 2; ++j) {                            \
      const int ro = so + brow + (QOFF) + j * 2048;                            \
      DST[j][0] = *(const bf16x8*)(sm + ro + colp0);                           \
      DST[j][1] = *(const bf16x8*)(sm + ro + colp1);                           \
    } } while (0)

#define MFMA_Q(I0, J0, BREG) do {                                              \
    __builtin_amdgcn_s_setprio(1);                                            \
    _Pragma("unroll") for (int i = 0; i < 4; ++i)                              \
      _Pragma("unroll") for (int j = 0; j < 2; ++j) {                          \
        acc[(I0) + i][(J0) + j] = __builtin_amdgcn_mfma_f32_16x16x32_bf16(     \
            a[i][0], BREG[j][0], acc[(I0) + i][(J0) + j], 0, 0, 0);            \
        acc[(I0) + i][(J0) + j] = __builtin_amdgcn_mfma_f32_16x16x32_bf16(     \
            a[i][1], BREG[j][1], acc[(I0) + i][(J0) + j], 0, 0, 0);            \
      }                                                                        \
    __builtin_amdgcn_s_setprio(0);                                            \
  } while (0)

#define SYNC_PRE_MFMA() do {                                                   \
    __builtin_amdgcn_s_barrier();                                              \
    asm volatile("s_waitcnt lgkmcnt(0)" ::: "memory");                         \
    __builtin_amdgcn_sched_barrier(0);                                         \
  } while (0)

__global__ __launch_bounds__(512, 2) void gemm_8phase(
    const short* __restrict__ A,   // [MDIM, KDIM] bf16
    const short* __restrict__ B,   // [NDIM, KDIM] bf16 (signs)
    const float* __restrict__ bias,
    float* __restrict__ C) {
  __shared__ __align__(16) char sm[131072];

  const int t    = threadIdx.x;
  const int lane = t & 63;
  const int w    = t >> 6;        // wave 0..7
  const int wm   = w >> 2;        // 0..1: rows wm*128..+128
  const int wn   = w & 3;         // 0..3: cols wn*64..+64
  const int fr   = lane & 15;
  const int g    = lane >> 4;     // k-group 0..3

  // T1: bijective XCD swizzle (nwg = 512 = 8 XCDs x 64)
  const int bid = blockIdx.y * gridDim.x + blockIdx.x;
  const int swz = (bid & 7) * 64 + (bid >> 3);
  const int bm  = (swz >> 4) << 8;   // 0..7936
  const int bn  = (swz & 15) << 8;   // 0..3840

  // fragment-read constants (T2 swizzle: XOR (row&7)<<4 into the column byte)
  const int sx    = (fr & 7) << 4;
  const int colp0 = (g << 4) ^ sx;          // kk=0: col-byte g*16
  const int colp1 = (64 | (g << 4)) ^ sx;   // kk=1: col-byte 64 + g*16
  const int arow  = (wm * 128 + fr) * 128;
  const int brow  = 32768 + (wn * 64 + fr) * 128;

  // staging constants (pre-swizzled global source column)
  const int srow = t >> 3;                        // 0..63
  const int scol = ((t & 7) ^ (srow & 7)) << 3;   // in shorts
  const short* aA = A + (size_t)(bm + srow) * KDIM + scol;
  const short* aB = B + (size_t)(bn + srow) * KDIM + scol;
  char* ldst = (char*)sm + t * 16;

  f32x4 acc[8][4] = {};
  bf16x8 a[4][2], b0[2][2], b1[2][2];

  // ---- prologue: stage kt0 fully + A0 of kt1; wait for kt0 (leave 1 half in flight)
  STAGE(0, 0, 0);
  STAGE(0, 1, 0);
  STAGE(0, 2, 0);
  STAGE(0, 3, 0);
  STAGE(1, 0, 1);
  asm volatile("s_waitcnt vmcnt(2)" ::: "memory");
  __builtin_amdgcn_s_barrier();

  for (int kt = 0; kt < NT; ++kt) {
    const int so = (kt & 1) << 16;   // current buffer byte offset
    const int nb = (kt & 1) ^ 1;     // next buffer index
    const int cb = (kt & 1);         // current buffer index

    // ---- phase 0: read A[qm=0] + B[qn=0]; stage A1(kt+1); MFMA Q(0,0)
    READ_A(0);
    READ_B(b0, 0);
    if (kt + 1 < NT) STAGE(nb, 1, kt + 1);
    SYNC_PRE_MFMA();
    MFMA_Q(0, 0, b0);
    __builtin_amdgcn_s_barrier();

    // ---- phase 1: read B[qn=1]; stage B0(kt+1); MFMA Q(0,1)
    READ_B(b1, 4096);
    if (kt + 1 < NT) STAGE(nb, 2, kt + 1);
    SYNC_PRE_MFMA();
    MFMA_Q(0, 2, b1);
    __builtin_amdgcn_s_barrier();

    // ---- phase 2: read A[qm=1]; stage B1(kt+1); MFMA Q(1,1)
    READ_A(8192);
    if (kt + 1 < NT) STAGE(nb, 3, kt + 1);
    SYNC_PRE_MFMA();
    MFMA_Q(4, 2, b1);
    __builtin_amdgcn_s_barrier();

    // ---- phase 3: stage A0(kt+2) into current buffer (all reads of it done);
    //      MFMA Q(1,0); single counted vmcnt per K-tile (never 0 mid-loop).
    if (kt + 2 < NT) STAGE(cb, 0, kt + 2);
    __builtin_amdgcn_s_barrier();
    MFMA_Q(4, 0, b0);
    if (kt + 2 < NT) {
      asm volatile("s_waitcnt vmcnt(2)" ::: "memory");  // all kt+1 halves landed
    } else {
      asm volatile("s_waitcnt vmcnt(0)" ::: "memory");  // tail: drain
    }
    __builtin_amdgcn_s_barrier();
  }

  // ---- epilogue: C/D layout col = lane&15, row = (lane>>4)*4 + r
  const int crow = bm + wm * 128;
  const int ccol = bn + wn * 64 + fr;
#pragma unroll
  for (int jj = 0; jj < 4; ++jj) {
    const int gc = ccol + jj * 16;
    const float bs = fsign(bias[gc]);
#pragma unroll
    for (int ii = 0; ii < 8; ++ii) {
      float* cp = C + (size_t)(crow + ii * 16 + g * 4) * NDIM + gc;
#pragma unroll
      for (int r = 0; r < 4; ++r)
        cp[(size_t)r * NDIM] = acc[ii][jj][r] + bs;
    }
  }
}

// ---------------- fallback: fused conversion GEMM (no workspace) ----------------

__global__ __launch_bounds__(256) void gemm_fused(
    const float* __restrict__ A,   // [MDIM, KDIM] fp32
    const float* __restrict__ W,   // [NDIM, KDIM] fp32
    const float* __restrict__ bias,
    float* __restrict__ C) {
  __shared__ short As[128 * 32];
  __shared__ short Bs[128 * 32];

  const int t    = threadIdx.x;
  const int lane = t & 63;
  const int wm   = (t >> 6) >> 1;
  const int wn   = (t >> 6) & 1;

  const int bm = blockIdx.y * 128;
  const int bn = blockIdx.x * 128;

  f32x4 acc[4][4] = {};

  const int srow = t >> 1;
  const int scol = (t & 1) << 4;

  const float* pA = A + (size_t)(bm + srow) * KDIM + scol;
  const float* pW = W + (size_t)(bn + srow) * KDIM + scol;
  short* sA = As + srow * 32 + scol;
  short* sB = Bs + srow * 32 + scol;

  const int fr  = lane & 15;
  const int fkB = (lane >> 4) << 4;

  for (int k0 = 0; k0 < KDIM; k0 += 32) {
    float4 va[4], vb[4];
#pragma unroll
    for (int q = 0; q < 4; ++q) {
      va[q] = *(const float4*)(pA + k0 + q * 4);
      vb[q] = *(const float4*)(pW + k0 + q * 4);
    }
    __syncthreads();
    short va_s[16], vb_s[16];
#pragma unroll
    for (int q = 0; q < 4; ++q) {
      va_s[q * 4 + 0] = f2bf(va[q].x); va_s[q * 4 + 1] = f2bf(va[q].y);
      va_s[q * 4 + 2] = f2bf(va[q].z); va_s[q * 4 + 3] = f2bf(va[q].w);
      vb_s[q * 4 + 0] = signbf(vb[q].x); vb_s[q * 4 + 1] = signbf(vb[q].y);
      vb_s[q * 4 + 2] = signbf(vb[q].z); vb_s[q * 4 + 3] = signbf(vb[q].w);
    }
    bf16x8 ca, cbv;
#pragma unroll
    for (int e = 0; e < 8; ++e) { ca[e] = va_s[e]; cbv[e] = vb_s[e]; }
    *(bf16x8*)(sA) = ca;
    *(bf16x8*)(sB) = cbv;
#pragma unroll
    for (int e = 0; e < 8; ++e) { ca[e] = va_s[8 + e]; cbv[e] = vb_s[8 + e]; }
    *(bf16x8*)(sA + 8) = ca;
    *(bf16x8*)(sB + 8) = cbv;
    __syncthreads();

    bf16x8 af[4], bfr[4];
#pragma unroll
    for (int i = 0; i < 4; ++i) {
      af[i]  = *(const bf16x8*)((const char*)As + (wm * 64 + i * 16 + fr) * 64 + fkB);
      bfr[i] = *(const bf16x8*)((const char*)Bs + (wn * 64 + i * 16 + fr) * 64 + fkB);
    }
#pragma unroll
    for (int i = 0; i < 4; ++i)
#pragma unroll
      for (int j = 0; j < 4; ++j)
        acc[i][j] = __builtin_amdgcn_mfma_f32_16x16x32_bf16(af[i], bfr[j], acc[i][j], 0, 0, 0);
  }
  __syncthreads();

  const int row0 = bm + wm * 64 + ((lane >> 4) << 2);
  const int col0 = bn + wn * 64 + (lane & 15);
#pragma unroll
  for (int j = 0; j < 4; ++j) {
    const int gc = col0 + j * 16;
    const float bs = fsign(bias[gc]);
#pragma unroll
    for (int i = 0; i < 4; ++i) {
      float* cp = C + (size_t)(row0 + i * 16) * NDIM + gc;
#pragma unroll
      for (int r = 0; r < 4; ++r)
        cp[(size_t)r * NDIM] = acc[i][j][r] + bs;
    }
  }
}

extern "C" void kernel_launch(void* const* d_in, const int* in_sizes, int n_in,
                              void* d_out, int out_size, void* d_ws, size_t ws_size,
                              hipStream_t stream) {
  const float* x    = (const float*)d_in[0];
  const float* w    = (const float*)d_in[1];
  const float* bias = (const float*)d_in[2];
  float* out = (float*)d_out;

  const size_t xb_bytes = (size_t)MDIM * KDIM * 2;   // 67.1 MB
  const size_t wb_bytes = (size_t)NDIM * KDIM * 2;   // 33.6 MB

  if (ws_size >= xb_bytes + wb_bytes) {
    short* xb = (short*)d_ws;
    short* wb = (short*)((char*)d_ws + xb_bytes);
    cvt_x_kernel<<<(MDIM * (KDIM / 4)) / 256, 256, 0, stream>>>(x, xb);
    cvt_w_kernel<<<(NDIM * (KDIM / 4)) / 256, 256, 0, stream>>>(w, wb);
    dim3 grid(NDIM / 256, MDIM / 256);   // 16 x 32 = 512 blocks
    gemm_8phase<<<grid, 512, 0, stream>>>(xb, wb, bias, out);
  } else {
    dim3 grid(NDIM / 128, MDIM / 128);
    gemm_fused<<<grid, 256, 0, stream>>>(x, w, bias, out);
  }
}